// Round 3
// baseline (626.494 us; speedup 1.0000x reference)
//
#include <hip/hip_runtime.h>
#include <cstdint>
#include <cstddef>

constexpr int DIMS = 128;

typedef __attribute__((ext_vector_type(8))) short bf16x8;
typedef __attribute__((ext_vector_type(8))) unsigned short ushort8v;
typedef __attribute__((ext_vector_type(4))) float f32x4;

__device__ __forceinline__ unsigned short f2b(float f) {
    uint32_t u = __builtin_bit_cast(uint32_t, f);
    uint32_t r = (u + 0x7FFFu + ((u >> 16) & 1u)) >> 16;
    return (unsigned short)r;
}
__device__ __forceinline__ float b2f(unsigned short h) {
    uint32_t u = ((uint32_t)h) << 16;
    return __builtin_bit_cast(float, u);
}

// ---------------- degree ----------------
__global__ void k_count(const int* __restrict__ dst, int* __restrict__ cnt, int E) {
    int e = blockIdx.x * blockDim.x + threadIdx.x;
    if (e < E) atomicAdd(&cnt[dst[e]], 1);
}

__global__ void k_dinv2(const int* __restrict__ cnt, float* __restrict__ dinv, int N) {
    int i = blockIdx.x * blockDim.x + threadIdx.x;
    if (i < N) dinv[i] = rsqrtf((float)(cnt[i] + 1));
}

// bump-allocated CSR row offsets (buckets need not be ordered)
__global__ void k_alloc(const int* __restrict__ cnt, int* __restrict__ row_ptr,
                        int* __restrict__ bump, int N) {
    int i = blockIdx.x * blockDim.x + threadIdx.x;
    int lane = threadIdx.x & 63;
    int v = (i < N) ? cnt[i] : 0;
    int x = v;
#pragma unroll
    for (int d = 1; d < 64; d <<= 1) {
        int y = __shfl_up(x, d);
        if (lane >= d) x += y;
    }
    int total = __shfl(x, 63);
    int base = 0;
    if (lane == 0) base = atomicAdd(bump, total);
    base = __shfl(base, 0);
    if (i < N) row_ptr[i] = base + x - v;
}

__global__ void k_fill(const int* __restrict__ src, const int* __restrict__ dst,
                       const int* __restrict__ row_ptr, int* __restrict__ cursor,
                       const float* __restrict__ dinv,
                       int* __restrict__ col, float* __restrict__ wgt, int E) {
    int e = blockIdx.x * blockDim.x + threadIdx.x;
    if (e >= E) return;
    int s = src[e], d = dst[e];
    int pos = row_ptr[d] + atomicAdd(&cursor[d], 1);
    col[pos] = s;
    wgt[pos] = dinv[s] * dinv[d];
}

// ---------------- f32 -> bf16 row cast (8 elems/thread) ----------------
__global__ void k_cast(const float* __restrict__ X, unsigned short* __restrict__ Y, int n8) {
    int i = blockIdx.x * blockDim.x + threadIdx.x;
    if (i >= n8) return;
    const float4* p = (const float4*)X + (size_t)i * 2;
    float4 a = p[0], b = p[1];
    ushort8v o;
    o[0] = f2b(a.x); o[1] = f2b(a.y); o[2] = f2b(a.z); o[3] = f2b(a.w);
    o[4] = f2b(b.x); o[5] = f2b(b.y); o[6] = f2b(b.z); o[7] = f2b(b.w);
    *(ushort8v*)&Y[(size_t)i * 8] = o;
}

// ---------------- W pack: f32 [128][128] -> bf16 hi/lo MFMA-fragment layout ----
// frag index ((kk*8+nt)*64+lane)*8 ; element j = W[kk*32+(lane>>4)*8+j][nt*16+(lane&15)]
__global__ void k_wpack(const float* __restrict__ W, unsigned short* __restrict__ hi,
                        unsigned short* __restrict__ lo) {
    int t = blockIdx.x * blockDim.x + threadIdx.x;  // 0..2047
    if (t >= 2048) return;
    int lane = t & 63;
    int nt = (t >> 6) & 7;
    int kk = t >> 9;
    int n = nt * 16 + (lane & 15);
    int k0 = kk * 32 + (lane >> 4) * 8;
    ushort8v h8, l8;
#pragma unroll
    for (int j = 0; j < 8; ++j) {
        float w = W[(size_t)(k0 + j) * DIMS + n];
        unsigned short h = f2b(w);
        h8[j] = h;
        l8[j] = f2b(w - b2f(h));
    }
    *(ushort8v*)&hi[(size_t)t * 8] = h8;
    *(ushort8v*)&lo[(size_t)t * 8] = l8;
}

// ---------------- gather (bf16 rows): agg = \hat{A} @ X ----------------
__global__ __launch_bounds__(256) void k_gather_b(
    const unsigned short* __restrict__ Xb, const float* __restrict__ dinv,
    const int* __restrict__ row_ptr, const int* __restrict__ cnt,
    const int* __restrict__ col, const float* __restrict__ wgt,
    float* __restrict__ agg, int N)
{
    int t = blockIdx.x * blockDim.x + threadIdx.x;
    int node = t >> 5;
    if (node >= N) return;
    int lane = t & 31;

    float ds = dinv[node];
    float w0 = ds * ds;
    ushort4 sv = *(const ushort4*)&Xb[(size_t)node * DIMS + lane * 4];
    float ax = b2f(sv.x) * w0, ay = b2f(sv.y) * w0, az = b2f(sv.z) * w0, aw = b2f(sv.w) * w0;

    int beg = row_ptr[node];
    int m = cnt[node];
    int j = 0;
    for (; j + 1 < m; j += 2) {
        int s0 = col[beg + j], s1 = col[beg + j + 1];
        float wa = wgt[beg + j], wb = wgt[beg + j + 1];
        ushort4 v0 = *(const ushort4*)&Xb[(size_t)s0 * DIMS + lane * 4];
        ushort4 v1 = *(const ushort4*)&Xb[(size_t)s1 * DIMS + lane * 4];
        ax = fmaf(wa, b2f(v0.x), ax); ay = fmaf(wa, b2f(v0.y), ay);
        az = fmaf(wa, b2f(v0.z), az); aw = fmaf(wa, b2f(v0.w), aw);
        ax = fmaf(wb, b2f(v1.x), ax); ay = fmaf(wb, b2f(v1.y), ay);
        az = fmaf(wb, b2f(v1.z), az); aw = fmaf(wb, b2f(v1.w), aw);
    }
    if (j < m) {
        int s0 = col[beg + j];
        float wa = wgt[beg + j];
        ushort4 v0 = *(const ushort4*)&Xb[(size_t)s0 * DIMS + lane * 4];
        ax = fmaf(wa, b2f(v0.x), ax); ay = fmaf(wa, b2f(v0.y), ay);
        az = fmaf(wa, b2f(v0.z), az); aw = fmaf(wa, b2f(v0.w), aw);
    }
    float4 o = {ax, ay, az, aw};
    *(float4*)&agg[(size_t)node * DIMS + lane * 4] = o;
}

// ---------------- MFMA dual-GEMM + coupling ----------------
// s = tanh(A@Ws+bs); t = A@Wt+bt; Out = Xo*exp(s)+t; optional bf16 copy OutB.
// Split-precision: A ~ ahi+alo (bf16), W ~ whi+wlo: A@W ~ ahi whi + alo whi + ahi wlo.
// A may alias Out (wave reads only its own 16 rows before writing them).
__global__ __launch_bounds__(256) void k_mfma_couple(
    const float* __restrict__ A,
    const unsigned short* __restrict__ WsHi, const unsigned short* __restrict__ WsLo,
    const unsigned short* __restrict__ WtHi, const unsigned short* __restrict__ WtLo,
    const float* __restrict__ bs, const float* __restrict__ bt,
    const float* __restrict__ Xo, float* __restrict__ Out,
    unsigned short* OutB, int N)
{
    int tid = threadIdx.x;
    int wave = tid >> 6, lane = tid & 63;
    int rbase = blockIdx.x * 64 + wave * 16;

    int arow = rbase + (lane & 15);
    if (arow >= N) arow = N - 1;
    int acol = (lane >> 4) * 8;

    f32x4 acc_s[8], acc_t[8];
#pragma unroll
    for (int nt = 0; nt < 8; ++nt) {
        acc_s[nt] = (f32x4){0.f, 0.f, 0.f, 0.f};
        acc_t[nt] = (f32x4){0.f, 0.f, 0.f, 0.f};
    }

#pragma unroll
    for (int kk = 0; kk < 4; ++kk) {
        const float* ap = &A[(size_t)arow * DIMS + kk * 32 + acol];
        float4 a0 = *(const float4*)ap;
        float4 a1 = *(const float4*)(ap + 4);
        float av[8] = {a0.x, a0.y, a0.z, a0.w, a1.x, a1.y, a1.z, a1.w};
        bf16x8 ahi, alo;
#pragma unroll
        for (int j = 0; j < 8; ++j) {
            unsigned short h = f2b(av[j]);
            ahi[j] = (short)h;
            alo[j] = (short)f2b(av[j] - b2f(h));
        }
#pragma unroll
        for (int nt = 0; nt < 8; ++nt) {
            size_t fi = ((size_t)(kk * 8 + nt) * 64 + lane) * 8;
            bf16x8 wsh = *(const bf16x8*)&WsHi[fi];
            bf16x8 wsl = *(const bf16x8*)&WsLo[fi];
            bf16x8 wth = *(const bf16x8*)&WtHi[fi];
            bf16x8 wtl = *(const bf16x8*)&WtLo[fi];
            acc_s[nt] = __builtin_amdgcn_mfma_f32_16x16x32_bf16(ahi, wsh, acc_s[nt], 0, 0, 0);
            acc_s[nt] = __builtin_amdgcn_mfma_f32_16x16x32_bf16(alo, wsh, acc_s[nt], 0, 0, 0);
            acc_s[nt] = __builtin_amdgcn_mfma_f32_16x16x32_bf16(ahi, wsl, acc_s[nt], 0, 0, 0);
            acc_t[nt] = __builtin_amdgcn_mfma_f32_16x16x32_bf16(ahi, wth, acc_t[nt], 0, 0, 0);
            acc_t[nt] = __builtin_amdgcn_mfma_f32_16x16x32_bf16(alo, wth, acc_t[nt], 0, 0, 0);
            acc_t[nt] = __builtin_amdgcn_mfma_f32_16x16x32_bf16(ahi, wtl, acc_t[nt], 0, 0, 0);
        }
    }

    // epilogue: C layout col=lane&15, row=(lane>>4)*4+q
    int crow0 = rbase + (lane >> 4) * 4;
    int ccol = lane & 15;
#pragma unroll
    for (int nt = 0; nt < 8; ++nt) {
        int cg = nt * 16 + ccol;
        float bsv = bs[cg], btv = bt[cg];
#pragma unroll
        for (int q = 0; q < 4; ++q) {
            int rg = crow0 + q;
            if (rg < N) {
                float s = tanhf(acc_s[nt][q] + bsv);
                float tt = acc_t[nt][q] + btv;
                float xo = Xo[(size_t)rg * DIMS + cg];
                float o = xo * expf(s) + tt;
                Out[(size_t)rg * DIMS + cg] = o;
                if (OutB) OutB[(size_t)rg * DIMS + cg] = f2b(o);
            }
        }
    }
}

// ---------------- f32 fallback kernels (round-2 path) ----------------
__global__ __launch_bounds__(256) void k_gather(
    const float4* __restrict__ X4, const float* __restrict__ dinv,
    const int* __restrict__ row_ptr, const int* __restrict__ cnt,
    const int* __restrict__ col, const float* __restrict__ wgt,
    float4* __restrict__ agg4, int N)
{
    int t = blockIdx.x * blockDim.x + threadIdx.x;
    int node = t >> 5;
    if (node >= N) return;
    int lane = t & 31;
    float ds = dinv[node];
    float w0 = ds * ds;
    float4 acc = X4[(size_t)node * 32 + lane];
    acc.x *= w0; acc.y *= w0; acc.z *= w0; acc.w *= w0;
    int beg = row_ptr[node];
    int m = cnt[node];
    for (int j = 0; j < m; ++j) {
        int s0 = col[beg + j];
        float wa = wgt[beg + j];
        float4 v0 = X4[(size_t)s0 * 32 + lane];
        acc.x = fmaf(wa, v0.x, acc.x); acc.y = fmaf(wa, v0.y, acc.y);
        acc.z = fmaf(wa, v0.z, acc.z); acc.w = fmaf(wa, v0.w, acc.w);
    }
    agg4[(size_t)node * 32 + lane] = acc;
}

__global__ __launch_bounds__(256) void k_gemm_couple(
    const float* A, const float* __restrict__ Ws, const float* __restrict__ bs,
    const float* __restrict__ Wt, const float* __restrict__ bt,
    const float* __restrict__ Xo, float* Out, int N)
{
    constexpr int TM = 64, TK = 16;
    __shared__ float As[TK][TM + 4];
    __shared__ float Ss[TK][DIMS];
    __shared__ float St[TK][DIMS];
    const int tid = threadIdx.x;
    const int ty = tid >> 4, tx = tid & 15;
    const int r0 = ty * 4, c0 = tx * 8;
    const int block_row = blockIdx.x * TM;

    float acc_s[4][8], acc_t[4][8];
#pragma unroll
    for (int r = 0; r < 4; ++r)
#pragma unroll
        for (int c = 0; c < 8; ++c) { acc_s[r][c] = 0.f; acc_t[r][c] = 0.f; }

    const int ar = tid >> 2;
    const int aq = tid & 3;
    int arow = block_row + ar;
    if (arow >= N) arow = N - 1;

    for (int k0 = 0; k0 < DIMS; k0 += TK) {
        __syncthreads();
        {
            float4 v = *(const float4*)&A[(size_t)arow * DIMS + k0 + aq * 4];
            As[aq * 4 + 0][ar] = v.x;
            As[aq * 4 + 1][ar] = v.y;
            As[aq * 4 + 2][ar] = v.z;
            As[aq * 4 + 3][ar] = v.w;
        }
#pragma unroll
        for (int i = 0; i < 2; ++i) {
            int idx = tid + i * 256;
            int kk = idx >> 5;
            int j4 = idx & 31;
            *(float4*)&Ss[kk][j4 * 4] = *(const float4*)&Ws[(size_t)(k0 + kk) * DIMS + j4 * 4];
            *(float4*)&St[kk][j4 * 4] = *(const float4*)&Wt[(size_t)(k0 + kk) * DIMS + j4 * 4];
        }
        __syncthreads();
#pragma unroll
        for (int k = 0; k < TK; ++k) {
            float4 av = *(const float4*)&As[k][r0];
            float a[4] = {av.x, av.y, av.z, av.w};
            float ws8[8], wt8[8];
            *(float4*)&ws8[0] = *(const float4*)&Ss[k][c0];
            *(float4*)&ws8[4] = *(const float4*)&Ss[k][c0 + 4];
            *(float4*)&wt8[0] = *(const float4*)&St[k][c0];
            *(float4*)&wt8[4] = *(const float4*)&St[k][c0 + 4];
#pragma unroll
            for (int r = 0; r < 4; ++r)
#pragma unroll
                for (int c = 0; c < 8; ++c) {
                    acc_s[r][c] = fmaf(a[r], ws8[c], acc_s[r][c]);
                    acc_t[r][c] = fmaf(a[r], wt8[c], acc_t[r][c]);
                }
        }
    }

    float bsv[8], btv[8];
    *(float4*)&bsv[0] = *(const float4*)&bs[c0];
    *(float4*)&bsv[4] = *(const float4*)&bs[c0 + 4];
    *(float4*)&btv[0] = *(const float4*)&bt[c0];
    *(float4*)&btv[4] = *(const float4*)&bt[c0 + 4];
#pragma unroll
    for (int r = 0; r < 4; ++r) {
        int row = block_row + r0 + r;
        if (row < N) {
            float xo[8];
            *(float4*)&xo[0] = *(const float4*)&Xo[(size_t)row * DIMS + c0];
            *(float4*)&xo[4] = *(const float4*)&Xo[(size_t)row * DIMS + c0 + 4];
            float o[8];
#pragma unroll
            for (int c = 0; c < 8; ++c) {
                float s = tanhf(acc_s[r][c] + bsv[c]);
                float t = acc_t[r][c] + btv[c];
                o[c] = xo[c] * expf(s) + t;
            }
            *(float4*)&Out[(size_t)row * DIMS + c0] = *(const float4*)&o[0];
            *(float4*)&Out[(size_t)row * DIMS + c0 + 4] = *(const float4*)&o[4];
        }
    }
}

extern "C" void kernel_launch(void* const* d_in, const int* in_sizes, int n_in,
                              void* d_out, int out_size, void* d_ws, size_t ws_size,
                              hipStream_t stream) {
    const float* x_main  = (const float*)d_in[0];
    const float* x_guide = (const float*)d_in[1];
    const int*   ei      = (const int*)d_in[2];
    const float* Ws1 = (const float*)d_in[3];
    const float* bs1 = (const float*)d_in[4];
    const float* Wt1 = (const float*)d_in[5];
    const float* bt1 = (const float*)d_in[6];
    const float* Ws2 = (const float*)d_in[7];
    const float* bs2 = (const float*)d_in[8];
    const float* Wt2 = (const float*)d_in[9];
    const float* bt2 = (const float*)d_in[10];

    const int N = in_sizes[0] / DIMS;
    const int E = in_sizes[2] / 2;
    const int* src = ei;
    const int* dst = ei + E;

    float* out_main  = (float*)d_out;
    float* out_guide = out_main + (size_t)N * DIMS;
    float* agg = out_guide;  // scratch aliasing second output (written last)

    // ---- ws layout ----
    char* w = (char*)d_ws;
    size_t off = 0;
    auto alloc = [&](size_t bytes) { size_t o = off; off = (off + bytes + 15) & ~(size_t)15; return o; };
    int*   cnt     = (int*)(w + alloc((size_t)N * 4));
    int*   row_ptr = (int*)(w + alloc((size_t)N * 4));
    int*   cursor  = (int*)(w + alloc((size_t)N * 4));
    int*   bump    = (int*)(w + alloc(64));
    float* dinv    = (float*)(w + alloc((size_t)N * 4));
    int*   col     = (int*)(w + alloc((size_t)E * 4));
    float* wgt     = (float*)(w + alloc((size_t)E * 4));
    size_t needed2 = off;  // round-2 path requirement
    unsigned short* xb  = (unsigned short*)(w + alloc((size_t)N * DIMS * 2));
    unsigned short* wpk = (unsigned short*)(w + alloc((size_t)8 * 16384 * 2));
    size_t needed3 = off;

    const int gather_grid = (N * 32 + 255) / 256;
    const int gemm_grid   = (N + 63) / 64;

    // ---- CSR build (shared by both paths) ----
    hipMemsetAsync(cnt, 0, ((char*)(bump + 16)) - (char*)cnt, stream);
    k_count<<<(E + 255) / 256, 256, 0, stream>>>(dst, cnt, E);
    k_dinv2<<<(N + 255) / 256, 256, 0, stream>>>(cnt, dinv, N);
    k_alloc<<<(N + 255) / 256, 256, 0, stream>>>(cnt, row_ptr, bump, N);
    k_fill<<<(E + 255) / 256, 256, 0, stream>>>(src, dst, row_ptr, cursor, dinv, col, wgt, E);

    if (ws_size >= needed3) {
        unsigned short* Ws1Hi = wpk + 0 * 16384; unsigned short* Ws1Lo = wpk + 1 * 16384;
        unsigned short* Wt1Hi = wpk + 2 * 16384; unsigned short* Wt1Lo = wpk + 3 * 16384;
        unsigned short* Ws2Hi = wpk + 4 * 16384; unsigned short* Ws2Lo = wpk + 5 * 16384;
        unsigned short* Wt2Hi = wpk + 6 * 16384; unsigned short* Wt2Lo = wpk + 7 * 16384;

        k_wpack<<<8, 256, 0, stream>>>(Ws1, Ws1Hi, Ws1Lo);
        k_wpack<<<8, 256, 0, stream>>>(Wt1, Wt1Hi, Wt1Lo);
        k_wpack<<<8, 256, 0, stream>>>(Ws2, Ws2Hi, Ws2Lo);
        k_wpack<<<8, 256, 0, stream>>>(Wt2, Wt2Hi, Wt2Lo);

        const int n8 = N * DIMS / 8;
        k_cast<<<(n8 + 255) / 256, 256, 0, stream>>>(x_guide, xb, n8);

        // ---- stage 1 ----
        k_gather_b<<<gather_grid, 256, 0, stream>>>(xb, dinv, row_ptr, cnt, col, wgt, agg, N);
        k_mfma_couple<<<gemm_grid, 256, 0, stream>>>(agg, Ws1Hi, Ws1Lo, Wt1Hi, Wt1Lo,
                                                     bs1, bt1, x_main, out_main, xb, N);
        // ---- stage 2 ----
        k_gather_b<<<gather_grid, 256, 0, stream>>>(xb, dinv, row_ptr, cnt, col, wgt, agg, N);
        k_mfma_couple<<<gemm_grid, 256, 0, stream>>>(agg, Ws2Hi, Ws2Lo, Wt2Hi, Wt2Lo,
                                                     bs2, bt2, x_guide, out_guide, nullptr, N);
    } else {
        // ---- fallback: round-2 f32 path ----
        (void)needed2;
        k_gather<<<gather_grid, 256, 0, stream>>>((const float4*)x_guide, dinv, row_ptr, cnt,
                                                  col, wgt, (float4*)agg, N);
        k_gemm_couple<<<gemm_grid, 256, 0, stream>>>(agg, Ws1, bs1, Wt1, bt1, x_main, out_main, N);
        k_gather<<<gather_grid, 256, 0, stream>>>((const float4*)out_main, dinv, row_ptr, cnt,
                                                  col, wgt, (float4*)agg, N);
        k_gemm_couple<<<gemm_grid, 256, 0, stream>>>(agg, Ws2, bs2, Wt2, bt2, x_guide, out_guide, N);
    }
}